// Round 2
// baseline (3598.008 us; speedup 1.0000x reference)
//
#include <hip/hip_runtime.h>
#include <hip/hip_bf16.h>
#include <math.h>

#define NS 100000
#define NR 100000
#define NE 600000
#define SILU_NORM 1.679177f

// ---------------------------------------------------------------------------
// fctp: out[n,w] = scale * sum_u sum_v x[n,u] * y[n,v] * W[u*1024 + v*128 + w]
// f32 in / f32 out. 16 nodes/block, 256 threads: w = tid&127, g = tid>>7.
// ---------------------------------------------------------------------------
__global__ __launch_bounds__(256) void fctp_kernel(
    const float* __restrict__ x, const float* __restrict__ y,
    const float* __restrict__ W, float* __restrict__ out, float scale)
{
    __shared__ float xs[16][128];     // 8 KB
    __shared__ float ys[16][8];       // 0.5 KB
    __shared__ float Wc[8 * 8 * 128]; // 32 KB (u-chunk of 8)

    const int tid = threadIdx.x;
    const int w = tid & 127, g = tid >> 7;
    const int n0 = blockIdx.x * 16;

    // stage x tile (2048 floats = 512 float4)
    {
        const float4* xg = (const float4*)(x + (size_t)n0 * 128);
        for (int j = tid; j < 512; j += 256) ((float4*)xs)[j] = xg[j];
    }
    if (tid < 128)
        ys[tid >> 3][tid & 7] = y[(size_t)(n0 + (tid >> 3)) * 8 + (tid & 7)];
    __syncthreads();

    float yr[8][8];
    #pragma unroll
    for (int i = 0; i < 8; ++i)
        #pragma unroll
        for (int v = 0; v < 8; ++v) yr[i][v] = ys[g * 8 + i][v];

    float acc[8];
    #pragma unroll
    for (int i = 0; i < 8; ++i) acc[i] = 0.f;

    for (int u0 = 0; u0 < 128; u0 += 8) {
        __syncthreads();
        {
            const float4* Wg = (const float4*)(W + (size_t)u0 * 1024);
            for (int j = tid; j < 2048; j += 256) ((float4*)Wc)[j] = Wg[j];
        }
        __syncthreads();
        #pragma unroll
        for (int u8 = 0; u8 < 8; u8 += 4) {
            float4 xv[8];
            #pragma unroll
            for (int i = 0; i < 8; ++i)
                xv[i] = *(const float4*)&xs[g * 8 + i][u0 + u8];
            #pragma unroll
            for (int du = 0; du < 4; ++du) {
                float wv[8];
                #pragma unroll
                for (int v = 0; v < 8; ++v)
                    wv[v] = Wc[((u8 + du) * 8 + v) * 128 + w];
                #pragma unroll
                for (int i = 0; i < 8; ++i) {
                    float t = yr[i][0] * wv[0];
                    #pragma unroll
                    for (int v = 1; v < 8; ++v) t += yr[i][v] * wv[v];
                    acc[i] += reinterpret_cast<const float*>(&xv[i])[du] * t;
                }
            }
        }
    }
    #pragma unroll
    for (int i = 0; i < 8; ++i)
        out[(size_t)(n0 + g * 8 + i) * 128 + w] = acc[i] * scale;
}

// ---------------------------------------------------------------------------
// Edge kernel: 32 edges/block, 256 threads. Phase 1: fc1+silu -> hs[32][128].
// Phase 2: fc2 with W2 staged in two 32KB halves. 4-edge x 4-w register tiles,
// float4 LDS reads. Epilogue: gather sf[src], * eattr, atomicAdd rfeat[dst].
// ---------------------------------------------------------------------------
__global__ __launch_bounds__(256) void edge_kernel(
    const int* __restrict__ esrc, const int* __restrict__ edst,
    const float* __restrict__ eattr,   // [E]
    const float* __restrict__ escal,   // [E,64]
    const float* __restrict__ W1,      // [64,128]
    const float* __restrict__ W2,      // [128,128]
    const float* __restrict__ sf,      // [NS,128]
    float* __restrict__ rfeat)         // [NR,128] f32 accum
{
    __shared__ float Wb[64 * 128];   // 32 KB (W1, then W2 halves)
    __shared__ float ess[32][64];    // 8 KB
    __shared__ float hs[32][128];    // 16 KB

    const int tid = threadIdx.x;
    const int et = tid >> 5;          // 0..7 -> edges et*4 .. et*4+3
    const int wq = (tid & 31) * 4;    // w0 of the 4-wide w tile
    const int e0 = blockIdx.x * 32;

    // stage escal tile (2048 floats) and W1 (8192 floats)
    {
        const float4* eg = (const float4*)(escal + (size_t)e0 * 64);
        for (int j = tid; j < 512; j += 256) ((float4*)ess)[j] = eg[j];
        const float4* wg = (const float4*)W1;
        for (int j = tid; j < 2048; j += 256) ((float4*)Wb)[j] = wg[j];
    }
    __syncthreads();

    // fc1: h[4 edges][4 w]
    float h[4][4];
    #pragma unroll
    for (int e = 0; e < 4; ++e)
        #pragma unroll
        for (int d = 0; d < 4; ++d) h[e][d] = 0.f;

    for (int k4 = 0; k4 < 16; ++k4) {
        float4 ev[4], wv[4];
        #pragma unroll
        for (int e = 0; e < 4; ++e)
            ev[e] = *(const float4*)&ess[et * 4 + e][k4 * 4];
        #pragma unroll
        for (int dk = 0; dk < 4; ++dk)
            wv[dk] = *(const float4*)&Wb[(k4 * 4 + dk) * 128 + wq];
        #pragma unroll
        for (int e = 0; e < 4; ++e)
            #pragma unroll
            for (int dk = 0; dk < 4; ++dk) {
                float ek = reinterpret_cast<const float*>(&ev[e])[dk];
                #pragma unroll
                for (int dw = 0; dw < 4; ++dw)
                    h[e][dw] += ek * reinterpret_cast<const float*>(&wv[dk])[dw];
            }
    }
    // silu + store hidden
    #pragma unroll
    for (int e = 0; e < 4; ++e) {
        float4 o;
        #pragma unroll
        for (int d = 0; d < 4; ++d) {
            float t = h[e][d] * 0.125f;                 // 1/sqrt(64)
            reinterpret_cast<float*>(&o)[d] =
                SILU_NORM * t / (1.f + expf(-t));
        }
        *(float4*)&hs[et * 4 + e][wq] = o;
    }
    __syncthreads();

    // fc2 in two 64-k halves
    float wt[4][4];
    #pragma unroll
    for (int e = 0; e < 4; ++e)
        #pragma unroll
        for (int d = 0; d < 4; ++d) wt[e][d] = 0.f;

    for (int half = 0; half < 2; ++half) {
        __syncthreads();   // everyone done reading Wb before restage
        {
            const float4* wg = (const float4*)(W2 + (size_t)half * 8192);
            for (int j = tid; j < 2048; j += 256) ((float4*)Wb)[j] = wg[j];
        }
        __syncthreads();
        for (int k4 = 0; k4 < 16; ++k4) {
            const int kk = half * 64 + k4 * 4;
            float4 hv[4], wv[4];
            #pragma unroll
            for (int e = 0; e < 4; ++e)
                hv[e] = *(const float4*)&hs[et * 4 + e][kk];
            #pragma unroll
            for (int dk = 0; dk < 4; ++dk)
                wv[dk] = *(const float4*)&Wb[(k4 * 4 + dk) * 128 + wq];
            #pragma unroll
            for (int e = 0; e < 4; ++e)
                #pragma unroll
                for (int dk = 0; dk < 4; ++dk) {
                    float hk = reinterpret_cast<const float*>(&hv[e])[dk];
                    #pragma unroll
                    for (int dw = 0; dw < 4; ++dw)
                        wt[e][dw] += hk * reinterpret_cast<const float*>(&wv[dk])[dw];
                }
        }
    }

    // epilogue: weight * sf[src] * eattr -> atomicAdd rfeat[dst]
    #pragma unroll
    for (int e = 0; e < 4; ++e) {
        const int ge = e0 + et * 4 + e;
        const float ea = eattr[ge] * 0.08838834764831845f;   // fold 1/sqrt(128)
        const int src = esrc[ge], dst = edst[ge];
        float4 sv = *(const float4*)(sf + (size_t)src * 128 + wq);
        float* rp = rfeat + (size_t)dst * 128 + wq;
        atomicAdd(rp + 0, wt[e][0] * ea * sv.x);
        atomicAdd(rp + 1, wt[e][1] * ea * sv.y);
        atomicAdd(rp + 2, wt[e][2] * ea * sv.z);
        atomicAdd(rp + 3, wt[e][3] * ea * sv.w);
    }
}

// ---------------------------------------------------------------------------
// angle[n] = 0.1/(32*sqrt(32)) * sum_{u,v} rfeat[n,u]*rattr[n,v]*W3[u*8+v]
// one wave per node
// ---------------------------------------------------------------------------
__global__ __launch_bounds__(256) void angle_kernel(
    const float* __restrict__ rfeat, const float* __restrict__ rattr,
    const float* __restrict__ W3, float* __restrict__ angle)
{
    const int node = (int)((blockIdx.x * 256 + threadIdx.x) >> 6);
    const int lane = threadIdx.x & 63;
    float acc = 0.f;
    #pragma unroll
    for (int j = 0; j < 16; ++j) {
        int k = lane + 64 * j;      // k = u*8 + v
        int u = k >> 3, v = k & 7;
        acc += rfeat[(size_t)node * 128 + u] * rattr[(size_t)node * 8 + v] * W3[k];
    }
    #pragma unroll
    for (int off = 32; off; off >>= 1) acc += __shfl_down(acc, off);
    if (lane == 0) angle[node] = acc * 5.524271728019903e-4f; // 0.1/(32*sqrt32)
}

// ---------------------------------------------------------------------------
// Final: conv = fctp(rfeat, rattr, W_lin2) (pass A, scale 1/(32*sqrt32))
//        rsc  = fctp(rinput, rattr, W_sc)  (pass B, scale 1/32)
//        out  = cos(a)*rsc + sin(a)*conv
// ---------------------------------------------------------------------------
__global__ __launch_bounds__(256) void final_kernel(
    const float* __restrict__ rfeat, const float* __restrict__ rinput,
    const float* __restrict__ rattr, const float* __restrict__ W_lin2,
    const float* __restrict__ W_sc, const float* __restrict__ angle,
    float* __restrict__ out)
{
    __shared__ float xs1[16][128];    // rfeat tile
    __shared__ float xs2[16][128];    // rinput tile
    __shared__ float ys[16][8];
    __shared__ float Wc[8 * 8 * 128]; // 32 KB

    const int tid = threadIdx.x;
    const int w = tid & 127, g = tid >> 7;
    const int n0 = blockIdx.x * 16;

    {
        const float4* ag = (const float4*)(rfeat + (size_t)n0 * 128);
        const float4* bg = (const float4*)(rinput + (size_t)n0 * 128);
        for (int j = tid; j < 512; j += 256) {
            ((float4*)xs1)[j] = ag[j];
            ((float4*)xs2)[j] = bg[j];
        }
    }
    if (tid < 128)
        ys[tid >> 3][tid & 7] = rattr[(size_t)(n0 + (tid >> 3)) * 8 + (tid & 7)];
    __syncthreads();

    float yr[8][8];
    #pragma unroll
    for (int i = 0; i < 8; ++i)
        #pragma unroll
        for (int v = 0; v < 8; ++v) yr[i][v] = ys[g * 8 + i][v];

    float accA[8], accB[8];
    #pragma unroll
    for (int i = 0; i < 8; ++i) { accA[i] = 0.f; accB[i] = 0.f; }

    // pass A: W_lin2 on xs1 ; pass B: W_sc on xs2
    for (int pass = 0; pass < 2; ++pass) {
        const float* Wsrc = pass ? W_sc : W_lin2;
        for (int u0 = 0; u0 < 128; u0 += 8) {
            __syncthreads();
            {
                const float4* Wg = (const float4*)(Wsrc + (size_t)u0 * 1024);
                for (int j = tid; j < 2048; j += 256) ((float4*)Wc)[j] = Wg[j];
            }
            __syncthreads();
            #pragma unroll
            for (int u8 = 0; u8 < 8; u8 += 4) {
                float4 xv[8];
                #pragma unroll
                for (int i = 0; i < 8; ++i)
                    xv[i] = pass ? *(const float4*)&xs2[g * 8 + i][u0 + u8]
                                 : *(const float4*)&xs1[g * 8 + i][u0 + u8];
                #pragma unroll
                for (int du = 0; du < 4; ++du) {
                    float wv[8];
                    #pragma unroll
                    for (int v = 0; v < 8; ++v)
                        wv[v] = Wc[((u8 + du) * 8 + v) * 128 + w];
                    #pragma unroll
                    for (int i = 0; i < 8; ++i) {
                        float t = yr[i][0] * wv[0];
                        #pragma unroll
                        for (int v = 1; v < 8; ++v) t += yr[i][v] * wv[v];
                        float xval = reinterpret_cast<const float*>(&xv[i])[du];
                        if (pass) accB[i] += xval * t;
                        else      accA[i] += xval * t;
                    }
                }
            }
        }
    }

    #pragma unroll
    for (int i = 0; i < 8; ++i) {
        const int gn = n0 + g * 8 + i;
        const float a = angle[gn];
        const float conv = accA[i] * 0.005524271728019903f;  // 1/32/sqrt(32)
        const float rsc  = accB[i] * 0.03125f;               // 1/32
        out[(size_t)gn * 128 + w] = cosf(a) * rsc + sinf(a) * conv;
    }
}

// ---------------------------------------------------------------------------
extern "C" void kernel_launch(void* const* d_in, const int* in_sizes, int n_in,
                              void* d_out, int out_size, void* d_ws, size_t ws_size,
                              hipStream_t stream)
{
    const float* sender_input   = (const float*)d_in[0];
    const float* sender_attr    = (const float*)d_in[1];
    const float* receiver_input = (const float*)d_in[2];
    const float* receiver_attr  = (const float*)d_in[3];
    const int*   edge_src = (const int*)d_in[4];
    const int*   edge_dst = (const int*)d_in[5];
    const float* edge_attr = (const float*)d_in[6];
    const float* edge_scal = (const float*)d_in[7];
    const float* W_sc   = (const float*)d_in[8];
    const float* W_lin1 = (const float*)d_in[9];
    const float* W_fc1  = (const float*)d_in[10];
    const float* W_fc2  = (const float*)d_in[11];
    const float* W_lin2 = (const float*)d_in[12];
    const float* W_lin3 = (const float*)d_in[13];

    char* ws = (char*)d_ws;
    float* sf    = (float*)(ws);               // 51.2 MB  [NS,128]
    float* rfeat = (float*)(ws + 51200000);    // 51.2 MB  [NR,128]
    float* angle = (float*)(ws + 102400000);   // 0.4 MB   [NR]

    hipMemsetAsync(rfeat, 0, (size_t)NR * 128 * 4, stream);

    // sender_features = fctp(sender_input, sender_attr, W_lin1), scale 1/32
    fctp_kernel<<<NS / 16, 256, 0, stream>>>(
        sender_input, sender_attr, W_lin1, sf, 0.03125f);
    // per-edge FC net + gather + scatter-add (raw accumulation, scales folded later)
    edge_kernel<<<NE / 32, 256, 0, stream>>>(
        edge_src, edge_dst, edge_attr, edge_scal, W_fc1, W_fc2, sf, rfeat);
    // receiver_angle (scale folds 0.1 * 1/32 * 1/sqrt(32))
    angle_kernel<<<NR / 4, 256, 0, stream>>>(
        rfeat, receiver_attr, W_lin3, angle);
    // conv fctp + self-connection fctp + trig combine
    final_kernel<<<NR / 16, 256, 0, stream>>>(
        rfeat, receiver_input, receiver_attr, W_lin2, W_sc, angle,
        (float*)d_out);
}

// Round 3
// 816.401 us; speedup vs baseline: 4.4072x; 4.4072x over previous
//
#include <hip/hip_runtime.h>
#include <hip/hip_bf16.h>
#include <math.h>

#define NS 100000
#define NR 100000
#define NE 600000
#define SILU_NORM 1.679177f

typedef __attribute__((ext_vector_type(8))) short short8;
typedef __attribute__((ext_vector_type(4))) float f32x4;

static __device__ __forceinline__ short f2bf(float f) {
    return __builtin_bit_cast(short, __float2bfloat16(f));
}

#define GLDS16(g, l)                                                         \
    __builtin_amdgcn_global_load_lds(                                        \
        (const __attribute__((address_space(1))) unsigned int*)(const void*)(g), \
        (__attribute__((address_space(3))) unsigned int*)(void*)(l), 16, 0, 0)

// ---------------------------------------------------------------------------
// Pre-swizzle a weight matrix W[K][128] (f32, k = u*8+v) into frag-major bf16:
// flat = s*4096 + f*512 + quad*128 + wl*8 + j  <-  W[(s*32+quad*8+j)*128 + f*16+wl]
// so a B-fragment (16x16x32: lane holds B[k=quad*8+j][w=f*16+(lane&15)]) is a
// lane-contiguous ds_read_b128 at (f*64+lane)*16B within kstep chunk s.
// ---------------------------------------------------------------------------
__global__ void swz_kernel(const float* __restrict__ W,
                           __hip_bfloat16* __restrict__ out, int total)
{
    int idx = blockIdx.x * 256 + threadIdx.x;
    if (idx >= total) return;
    int s = idx >> 12, r = idx & 4095;
    int f = r >> 9;  r &= 511;
    int quad = r >> 7; r &= 127;
    int wl = r >> 3;
    int j = r & 7;
    int k = s * 32 + quad * 8 + j;
    int w = f * 16 + wl;
    out[idx] = __float2bfloat16(W[(size_t)k * 128 + w]);
}

// ---------------------------------------------------------------------------
// fctp via MFMA: out[n,w] = scale * sum_k A[n,k]*W[k,w], A[n,u*8+v]=x[n,u]*y[n,v]
// A-frag trick: lane (m=lane&15) holds A[m][quad*8 + 0..7] = x[m][u]*y[m][0..7]
// with u = kstep*4 + quad -> 8 f32 muls + cvt, no A staging.
// Block: 256 thr, 4 waves, 32 nodes/wave (2 m-tiles), 128 nodes/block.
// ---------------------------------------------------------------------------
__global__ __launch_bounds__(256) void fctp_mfma_kernel(
    const float* __restrict__ x, const float* __restrict__ y,
    const __hip_bfloat16* __restrict__ Wswz, float* __restrict__ out,
    float scale, int N)
{
    __shared__ __hip_bfloat16 Wb[8192];  // 16 KB: K=64 chunk (2 ksteps x 4096)
    __shared__ float xs[128 * 8];        // 4 KB: x[nodeLocal][c], u = cc*8+c

    const int tid = threadIdx.x;
    const int lane = tid & 63;
    const int wv = tid >> 6;
    const int quad = lane >> 4;
    const int wl = lane & 15;
    const int n0 = blockIdx.x * 128;

    // y for this lane's two m-tiles (row m = wl)
    float ya[2][8];
    #pragma unroll
    for (int mt = 0; mt < 2; ++mt) {
        int node = n0 + wv * 32 + mt * 16 + wl;
        if (node >= N) node = N - 1;
        const float4* yp = (const float4*)(y + (size_t)node * 8);
        float4 a = yp[0], b = yp[1];
        ya[mt][0] = a.x; ya[mt][1] = a.y; ya[mt][2] = a.z; ya[mt][3] = a.w;
        ya[mt][4] = b.x; ya[mt][5] = b.y; ya[mt][6] = b.z; ya[mt][7] = b.w;
    }

    f32x4 acc[2][8];
    #pragma unroll
    for (int mt = 0; mt < 2; ++mt)
        #pragma unroll
        for (int f = 0; f < 8; ++f)
            acc[mt][f] = (f32x4){0.f, 0.f, 0.f, 0.f};

    for (int cc = 0; cc < 16; ++cc) {          // K chunks of 64
        __syncthreads();
        // stage W chunk (16 KB) via direct-to-LDS DMA
        {
            const char* src = (const char*)(Wswz + (size_t)cc * 8192);
            #pragma unroll
            for (int i = 0; i < 4; ++i) {
                int off = (i * 256 + tid) * 16;
                GLDS16(src + off, (char*)Wb + off);
            }
            // stage x chunk: xs[n][c] = x[n0+n][cc*8+c], 4 KB
            int nl = tid >> 1, c4 = (tid & 1) * 4;
            int node = n0 + nl;
            if (node >= N) node = N - 1;
            GLDS16(x + (size_t)node * 128 + cc * 8 + c4, (char*)xs + tid * 16);
        }
        __syncthreads();

        #pragma unroll
        for (int ks = 0; ks < 2; ++ks) {
            short8 bfr[8];
            #pragma unroll
            for (int f = 0; f < 8; ++f)
                bfr[f] = *(const short8*)((const short*)Wb +
                                          (size_t)ks * 4096 + (f * 64 + lane) * 8);
            #pragma unroll
            for (int mt = 0; mt < 2; ++mt) {
                float xv = xs[(wv * 32 + mt * 16 + wl) * 8 + ks * 4 + quad];
                short8 af;
                #pragma unroll
                for (int v = 0; v < 8; ++v) af[v] = f2bf(xv * ya[mt][v]);
                #pragma unroll
                for (int f = 0; f < 8; ++f)
                    acc[mt][f] = __builtin_amdgcn_mfma_f32_16x16x32_bf16(
                        af, bfr[f], acc[mt][f], 0, 0, 0);
            }
        }
    }

    // C/D layout: col = lane&15 (=w within 16), row = quad*4 + reg (=node)
    #pragma unroll
    for (int mt = 0; mt < 2; ++mt) {
        #pragma unroll
        for (int r = 0; r < 4; ++r) {
            int node = n0 + wv * 32 + mt * 16 + quad * 4 + r;
            if (node < N) {
                #pragma unroll
                for (int f = 0; f < 8; ++f)
                    out[(size_t)node * 128 + f * 16 + wl] = acc[mt][f][r] * scale;
            }
        }
    }
}

// ---------------------------------------------------------------------------
// Edge kernel: fc1 (K=64) -> silu -> fc2 (K=128) via MFMA, then gather sf[src],
// * eattr, atomicAdd into rfeat[dst]. 128 edges/block, 4 waves x 2 m-tiles.
// h goes C-layout -> LDS (A-frag-major) -> A-operand for fc2.
// ---------------------------------------------------------------------------
__global__ __launch_bounds__(256) void edge_mfma_kernel(
    const int* __restrict__ esrc, const int* __restrict__ edst,
    const float* __restrict__ eattr, const float* __restrict__ escal,
    const __hip_bfloat16* __restrict__ W1swz,   // 8192  (K=64 swizzled)
    const __hip_bfloat16* __restrict__ W2swz,   // 16384 (K=128 swizzled)
    const float* __restrict__ sf, float* __restrict__ rfeat)
{
    __shared__ __hip_bfloat16 esA[8192];   // 16 KB  A-frag-major edge scalars
    __shared__ __hip_bfloat16 Wb[16384];   // 32 KB  W1 then W2
    __shared__ __hip_bfloat16 hA[16384];   // 32 KB  A-frag-major hidden

    const int tid = threadIdx.x;
    const int lane = tid & 63;
    const int wv = tid >> 6;
    const int quad = lane >> 4;
    const int wl = lane & 15;
    const int e0 = blockIdx.x * 128;

    // stage esA: flat chunk c = (s*8+mt)*64 + l holds es[mt*16+(l&15)][s*32+(l>>4)*8 + 0..7]
    #pragma unroll
    for (int i = 0; i < 4; ++i) {
        int c = i * 256 + tid;
        int l = c & 63, mtc = (c >> 6) & 7, s = c >> 9;
        int e = e0 + mtc * 16 + (l & 15);
        if (e >= NE) e = NE - 1;
        int kb = s * 32 + (l >> 4) * 8;
        const float4* p = (const float4*)(escal + (size_t)e * 64 + kb);
        float4 aa = p[0], bb = p[1];
        short8 v;
        v[0] = f2bf(aa.x); v[1] = f2bf(aa.y); v[2] = f2bf(aa.z); v[3] = f2bf(aa.w);
        v[4] = f2bf(bb.x); v[5] = f2bf(bb.y); v[6] = f2bf(bb.z); v[7] = f2bf(bb.w);
        *(short8*)((short*)esA + (size_t)c * 8) = v;
    }
    // stage W1 (16 KB)
    #pragma unroll
    for (int i = 0; i < 4; ++i) {
        int off = (i * 256 + tid) * 16;
        GLDS16((const char*)W1swz + off, (char*)Wb + off);
    }
    __syncthreads();

    // ---- fc1: [128 x 64] @ [64 x 128] ----
    f32x4 acc1[2][8];
    #pragma unroll
    for (int mt = 0; mt < 2; ++mt)
        #pragma unroll
        for (int f = 0; f < 8; ++f) acc1[mt][f] = (f32x4){0.f, 0.f, 0.f, 0.f};

    #pragma unroll
    for (int ks = 0; ks < 2; ++ks) {
        short8 bfr[8];
        #pragma unroll
        for (int f = 0; f < 8; ++f)
            bfr[f] = *(const short8*)((const short*)Wb +
                                      (size_t)ks * 4096 + (f * 64 + lane) * 8);
        #pragma unroll
        for (int mt = 0; mt < 2; ++mt) {
            int MT = wv * 2 + mt;
            short8 af = *(const short8*)((const short*)esA +
                                         ((size_t)(ks * 8 + MT) * 64 + lane) * 8);
            #pragma unroll
            for (int f = 0; f < 8; ++f)
                acc1[mt][f] = __builtin_amdgcn_mfma_f32_16x16x32_bf16(
                    af, bfr[f], acc1[mt][f], 0, 0, 0);
        }
    }

    // silu + write h to hA in fc2 A-frag order (scatter ds_write_u16)
    #pragma unroll
    for (int mt = 0; mt < 2; ++mt) {
        int MT = wv * 2 + mt;
        #pragma unroll
        for (int f = 0; f < 8; ++f) {
            int s2 = f >> 1;
            int q2 = ((f & 1) * 2 + (wl >> 3)) & 3;
            int j2 = wl & 7;
            #pragma unroll
            for (int r = 0; r < 4; ++r) {
                float t = acc1[mt][f][r] * 0.125f;              // 1/sqrt(64)
                float h = SILU_NORM * t / (1.f + __expf(-t));
                int lpos = q2 * 16 + quad * 4 + r;
                ((short*)hA)[((size_t)(s2 * 8 + MT) * 64 + lpos) * 8 + j2] = f2bf(h);
            }
        }
    }
    __syncthreads();   // fc1 done reading Wb; hA writes visible
    // stage W2 (32 KB)
    #pragma unroll
    for (int i = 0; i < 8; ++i) {
        int off = (i * 256 + tid) * 16;
        GLDS16((const char*)W2swz + off, (char*)Wb + off);
    }
    __syncthreads();

    // ---- fc2: [128 x 128] @ [128 x 128] ----
    f32x4 acc2[2][8];
    #pragma unroll
    for (int mt = 0; mt < 2; ++mt)
        #pragma unroll
        for (int f = 0; f < 8; ++f) acc2[mt][f] = (f32x4){0.f, 0.f, 0.f, 0.f};

    #pragma unroll
    for (int ks = 0; ks < 4; ++ks) {
        short8 bfr[8];
        #pragma unroll
        for (int f = 0; f < 8; ++f)
            bfr[f] = *(const short8*)((const short*)Wb +
                                      (size_t)ks * 4096 + (f * 64 + lane) * 8);
        #pragma unroll
        for (int mt = 0; mt < 2; ++mt) {
            int MT = wv * 2 + mt;
            short8 af = *(const short8*)((const short*)hA +
                                         ((size_t)(ks * 8 + MT) * 64 + lane) * 8);
            #pragma unroll
            for (int f = 0; f < 8; ++f)
                acc2[mt][f] = __builtin_amdgcn_mfma_f32_16x16x32_bf16(
                    af, bfr[f], acc2[mt][f], 0, 0, 0);
        }
    }

    // epilogue: wt * eattr' * sf[src] -> atomicAdd rfeat[dst]
    const float s128 = 0.08838834764831845f;   // 1/sqrt(128)
    #pragma unroll
    for (int mt = 0; mt < 2; ++mt) {
        int MT = wv * 2 + mt;
        #pragma unroll
        for (int r = 0; r < 4; ++r) {
            int e = e0 + MT * 16 + quad * 4 + r;
            if (e < NE) {
                int src = esrc[e], dst = edst[e];
                float ea = eattr[e] * s128;
                #pragma unroll
                for (int f = 0; f < 8; ++f) {
                    float val = acc2[mt][f][r] * ea *
                                sf[(size_t)src * 128 + f * 16 + wl];
                    atomicAdd(&rfeat[(size_t)dst * 128 + f * 16 + wl], val);
                }
            }
        }
    }
}

// ---------------------------------------------------------------------------
// angle[n] = 0.1/(32*sqrt(32)) * sum_{u,v} rfeat[n,u]*rattr[n,v]*W3[u*8+v]
// ---------------------------------------------------------------------------
__global__ __launch_bounds__(256) void angle_kernel(
    const float* __restrict__ rfeat, const float* __restrict__ rattr,
    const float* __restrict__ W3, float* __restrict__ angle)
{
    const int node = (int)((blockIdx.x * 256 + threadIdx.x) >> 6);
    const int lane = threadIdx.x & 63;
    float acc = 0.f;
    #pragma unroll
    for (int j = 0; j < 16; ++j) {
        int k = lane + 64 * j;
        int u = k >> 3, v = k & 7;
        acc += rfeat[(size_t)node * 128 + u] * rattr[(size_t)node * 8 + v] * W3[k];
    }
    #pragma unroll
    for (int off = 32; off; off >>= 1) acc += __shfl_down(acc, off);
    if (lane == 0) angle[node] = acc * 5.524271728019903e-4f;
}

// ---------------------------------------------------------------------------
// out = cos(a)*rsc + sin(a)*conv     (per float4)
// ---------------------------------------------------------------------------
__global__ __launch_bounds__(256) void combine_kernel(
    const float* __restrict__ conv, const float* __restrict__ rsc,
    const float* __restrict__ angle, float* __restrict__ out)
{
    int idx = blockIdx.x * 256 + threadIdx.x;      // over NR*128/4
    float a = angle[idx >> 5];
    float ca = __cosf(a), sa = __sinf(a);
    float4 c = ((const float4*)conv)[idx];
    float4 s = ((const float4*)rsc)[idx];
    float4 o;
    o.x = ca * s.x + sa * c.x;
    o.y = ca * s.y + sa * c.y;
    o.z = ca * s.z + sa * c.z;
    o.w = ca * s.w + sa * c.w;
    ((float4*)out)[idx] = o;
}

// ---------------------------------------------------------------------------
extern "C" void kernel_launch(void* const* d_in, const int* in_sizes, int n_in,
                              void* d_out, int out_size, void* d_ws, size_t ws_size,
                              hipStream_t stream)
{
    const float* sender_input   = (const float*)d_in[0];
    const float* sender_attr    = (const float*)d_in[1];
    const float* receiver_input = (const float*)d_in[2];
    const float* receiver_attr  = (const float*)d_in[3];
    const int*   edge_src  = (const int*)d_in[4];
    const int*   edge_dst  = (const int*)d_in[5];
    const float* edge_attr = (const float*)d_in[6];
    const float* edge_scal = (const float*)d_in[7];
    const float* W_sc   = (const float*)d_in[8];
    const float* W_lin1 = (const float*)d_in[9];
    const float* W_fc1  = (const float*)d_in[10];
    const float* W_fc2  = (const float*)d_in[11];
    const float* W_lin2 = (const float*)d_in[12];
    const float* W_lin3 = (const float*)d_in[13];

    char* ws = (char*)d_ws;
    float* sf    = (float*)(ws);               // 51.2 MB ; later reused as conv
    float* rfeat = (float*)(ws + 51200000);    // 51.2 MB ; later reused as rsc
    float* angle = (float*)(ws + 102400000);   // 0.4 MB
    __hip_bfloat16* Wl1s = (__hip_bfloat16*)(ws + 102800000);  // 262144 B
    __hip_bfloat16* Wscs = (__hip_bfloat16*)(ws + 103062144);  // 262144 B
    __hip_bfloat16* Wl2s = (__hip_bfloat16*)(ws + 103324288);  // 262144 B
    __hip_bfloat16* W1s  = (__hip_bfloat16*)(ws + 103586432);  // 16384 B
    __hip_bfloat16* W2s  = (__hip_bfloat16*)(ws + 103602816);  // 32768 B
    float* conv = sf;
    float* rsc  = rfeat;

    // weight pre-swizzles (one-time per launch, tiny)
    swz_kernel<<<512, 256, 0, stream>>>(W_lin1, Wl1s, 131072);
    swz_kernel<<<512, 256, 0, stream>>>(W_sc,   Wscs, 131072);
    swz_kernel<<<512, 256, 0, stream>>>(W_lin2, Wl2s, 131072);
    swz_kernel<<<32,  256, 0, stream>>>(W_fc1,  W1s,  8192);
    swz_kernel<<<64,  256, 0, stream>>>(W_fc2,  W2s,  16384);

    hipMemsetAsync(rfeat, 0, (size_t)NR * 128 * 4, stream);

    // sender_features = fctp(sender_input, sender_attr, W_lin1), scale 1/32
    fctp_mfma_kernel<<<(NS + 127) / 128, 256, 0, stream>>>(
        sender_input, sender_attr, Wl1s, sf, 0.03125f, NS);
    // edge FC + gather + scatter
    edge_mfma_kernel<<<(NE + 127) / 128, 256, 0, stream>>>(
        edge_src, edge_dst, edge_attr, edge_scal, W1s, W2s, sf, rfeat);
    // angle from raw rfeat
    angle_kernel<<<NR / 4, 256, 0, stream>>>(rfeat, receiver_attr, W_lin3, angle);
    // conv = fctp(rfeat, rattr, W_lin2) * 1/(32*sqrt(32))  (overwrites sf slot)
    fctp_mfma_kernel<<<(NR + 127) / 128, 256, 0, stream>>>(
        rfeat, receiver_attr, Wl2s, conv, 0.005524271728019903f, NR);
    // rsc = fctp(receiver_input, rattr, W_sc) * 1/32  (overwrites rfeat slot)
    fctp_mfma_kernel<<<(NR + 127) / 128, 256, 0, stream>>>(
        receiver_input, receiver_attr, Wscs, rsc, 0.03125f, NR);
    // final trig combine
    combine_kernel<<<NR * 128 / 4 / 256, 256, 0, stream>>>(
        conv, rsc, angle, (float*)d_out);
}